// Round 1
// baseline (409.698 us; speedup 1.0000x reference)
//
#include <hip/hip_runtime.h>
#include <stdint.h>

typedef __attribute__((ext_vector_type(8))) short bf16x8;
typedef __attribute__((ext_vector_type(8))) unsigned short u16x8;
typedef __attribute__((ext_vector_type(4))) float f32x4;

#define DEV __device__ __forceinline__

// ws layout in ushort elements
constexpr size_t WQ_PK    = 0;         // 65536 elems
constexpr size_t WPROJ_PK = 65536;     // 65536 elems
constexpr size_t WP_PK    = 131072;    // 4 * 131072 elems
constexpr size_t KVBUF    = 655360;    // 4096*2*8*21*32 = 44040192 elems

constexpr float SCALE_Q = 0.17677669529663687f;  // 32^-0.5

DEV uint16_t f2bf(float f){
  uint32_t u = __builtin_bit_cast(uint32_t, f);
  u += 0x7fffu + ((u >> 16) & 1u);
  return (uint16_t)(u >> 16);
}

// ---------------------------------------------------------------------------
// K0: prepack weights into MFMA B-fragment layout, f32 -> bf16.
// B-frag for (nt,kt): lane l, j=0..7 supplies B[k=kt*32+(l>>4)*8+j][n=nt*16+(l&15)]
// = W[n][k].  Stored at pk[((nt*8+kt)*64+l)*8 + j].
// ---------------------------------------------------------------------------
__global__ __launch_bounds__(256) void k_prepack(
    const float* __restrict__ wq,  const float* __restrict__ wp1,
    const float* __restrict__ wp2, const float* __restrict__ wp3,
    const float* __restrict__ wp4, const float* __restrict__ wproj,
    uint16_t* __restrict__ ws)
{
  int f = blockIdx.x * 256 + threadIdx.x;   // 0..81919 fragment id
  const float* src; uint16_t* dst; int g;
  if (f < 8192)       { src = wq;    dst = ws + WQ_PK;    g = f; }
  else if (f < 16384) { src = wproj; dst = ws + WPROJ_PK; g = f - 8192; }
  else {
    int j = (f - 16384) >> 14;
    src = j == 0 ? wp1 : j == 1 ? wp2 : j == 2 ? wp3 : wp4;
    dst = ws + WP_PK + (size_t)j * 131072;
    g = (f - 16384) & 16383;
  }
  int l = g & 63, kt = (g >> 6) & 7, nt = g >> 9;
  int n  = nt * 16 + (l & 15);
  int k0 = kt * 32 + (l >> 4) * 8;
  const float* s = src + (size_t)n * 256 + k0;
  u16x8 v;
  #pragma unroll
  for (int j = 0; j < 8; ++j) v[j] = f2bf(s[j]);
  *reinterpret_cast<u16x8*>(dst + (size_t)g * 8) = v;
}

// ---------------------------------------------------------------------------
// K1: depthwise convs + pointwise (MFMA) + gather -> kv buffer (bf16).
// 8 batches per block, 512 threads (8 waves).
// LDS: abuf [168][256] ushort, swizzled: byte = (row*512 + c*2) ^ ((row&7)<<4)
// ---------------------------------------------------------------------------
__global__ __launch_bounds__(512, 2) void k_kv(
    const float* __restrict__ x,
    const float* __restrict__ wd1, const float* __restrict__ bd1, const float* __restrict__ bp1,
    const float* __restrict__ wd2, const float* __restrict__ bd2, const float* __restrict__ bp2,
    const float* __restrict__ wd3, const float* __restrict__ bd3, const float* __restrict__ bp3,
    const float* __restrict__ wd4, const float* __restrict__ bd4, const float* __restrict__ bp4,
    const uint16_t* __restrict__ ws, uint16_t* __restrict__ kvbuf)
{
  extern __shared__ char smem[];  // 86016 B
  const int t = threadIdx.x, lane = t & 63, w = t >> 6;
  const int b0 = blockIdx.x * 8;

  constexpr int DILA[4] = {1,2,3,4}, PADA[4] = {0,0,1,2}, OWA[4] = {3,2,2,2};
  constexpr int HWA[4]  = {9,4,4,4}, OFFA[4] = {0,9,13,17}, MTA[4] = {5,2,2,2};

  // ---- depthwise conv, all branches; write dT (bf16) to LDS ----
  {
    const int c = t & 255, half = t >> 8;
    for (int pass = 0; pass < 4; ++pass){
      const int bh = pass * 2 + half;
      float xr[49];
      #pragma unroll
      for (int p = 0; p < 49; ++p)
        xr[p] = x[((size_t)(b0 + bh) * 49 + p) * 256 + c];
      #pragma unroll
      for (int j = 0; j < 4; ++j){
        const float* wdp = j==0?wd1:j==1?wd2:j==2?wd3:wd4;
        const float* bdp = j==0?bd1:j==1?bd2:j==2?bd3:bd4;
        float wv[9];
        #pragma unroll
        for (int q = 0; q < 9; ++q) wv[q] = wdp[c * 9 + q];
        const float bdv = bdp[c];
        #pragma unroll
        for (int oy = 0; oy < OWA[j]; ++oy)
        #pragma unroll
        for (int ox = 0; ox < OWA[j]; ++ox){
          float acc = bdv;
          #pragma unroll
          for (int ky = 0; ky < 3; ++ky){
            const int yy = oy * 2 - PADA[j] + ky * DILA[j];
            if (yy < 0 || yy > 6) continue;
            #pragma unroll
            for (int kx = 0; kx < 3; ++kx){
              const int xx = ox * 2 - PADA[j] + kx * DILA[j];
              if (xx < 0 || xx > 6) continue;
              acc += xr[yy * 7 + xx] * wv[ky * 3 + kx];
            }
          }
          const int row = bh * 21 + OFFA[j] + oy * OWA[j] + ox;
          *reinterpret_cast<uint16_t*>(smem + ((row * 512 + c * 2) ^ ((row & 7) << 4))) = f2bf(acc);
        }
      }
    }
  }
  __syncthreads();

  // ---- pointwise GEMM per branch + gather-write ----
  // wave w owns output cols [w*64, w*64+64)
  #pragma unroll
  for (int j = 0; j < 4; ++j){
    const uint16_t* pk = ws + WP_PK + (size_t)j * 131072;
    const float* bpp = j==0?bp1:j==1?bp2:j==2?bp3:bp4;
    const int hw = HWA[j], off = OFFA[j], MV = hw * 8;
    for (int mt = 0; mt < MTA[j]; ++mt){
      f32x4 acc[4] = {};
      const int mrow = mt * 16 + (lane & 15);
      const bool av = mrow < MV;
      const int bh = mrow / hw, s = mrow - bh * hw;
      const int arow = bh * 21 + off + s;
      const int abase = arow * 512 + (lane >> 4) * 16;
      #pragma unroll
      for (int kt = 0; kt < 8; ++kt){
        bf16x8 a = {};
        if (av) a = *reinterpret_cast<const bf16x8*>(smem + ((abase + kt * 64) ^ ((arow & 7) << 4)));
        #pragma unroll
        for (int nt = 0; nt < 4; ++nt){
          const int ntg = w * 4 + nt;
          bf16x8 bfr = *reinterpret_cast<const bf16x8*>(pk + (size_t)((ntg * 8 + kt) * 64 + lane) * 8);
          acc[nt] = __builtin_amdgcn_mfma_f32_16x16x32_bf16(a, bfr, acc[nt], 0, 0, 0);
        }
      }
      const int mr2 = mt * 16 + (lane >> 4) * 4;
      #pragma unroll
      for (int nt = 0; nt < 4; ++nt){
        const int o = w * 64 + nt * 16 + (lane & 15);
        const float bpv = bpp[o];
        const int r = o >> 1, e = o & 1, hh = r >> 5, d = r & 31;
        #pragma unroll
        for (int i = 0; i < 4; ++i){
          const int m = mr2 + i;
          if (m >= MV) continue;
          const int bh2 = m / hw, s2 = m - bh2 * hw;
          const int c2 = e * hw + s2, kind = c2 & 1, mg = off + (c2 >> 1);
          const float val = acc[nt][i] + bpv;
          kvbuf[((((size_t)(b0 + bh2) * 2 + kind) * 8 + hh) * 21 + mg) * 32 + d] = f2bf(val);
        }
      }
    }
  }
}

// ---------------------------------------------------------------------------
// K2: fused q-proj + attention + out-proj. 2 batches/block (M=128, batch = 64
// padded rows), 512 threads (8 waves). GEMM split: wave=(gm,gn)=2x4 groups,
// 4 Mtiles x 4 Ntiles per wave. Attention: wave w <-> head w.
// ---------------------------------------------------------------------------
__global__ __launch_bounds__(512, 2) void k_attn(
    const float* __restrict__ x, const float* __restrict__ bq,
    const float* __restrict__ bproj, const uint16_t* __restrict__ ws,
    float* __restrict__ out)
{
  extern __shared__ char smem[];
  constexpr int OS = 0;        // [128][256] us, q then O, swz(row)
  constexpr int KS = 65536;    // [8][32][32]  us, K[m][d], swz(m)
  constexpr int VT = 81920;    // [8][32][32]  us, V^T[d][m], swz(d)
  constexpr int PA = 98304;    // [8][64][32]  us, P[row][m], swz(row)
  constexpr int XS = 131072;   // [128][32]    us, x K-slice, swz(row)
  constexpr int BS = 139264;   // [16][64][8]  us, B-frag stage, linear
  // total 155648 B

  const int t = threadIdx.x, lane = t & 63, w = t >> 6;
  const int gm = w >> 2, gn = w & 3;
  const int b0 = blockIdx.x * 2;
  const uint16_t* wq_pk    = ws + WQ_PK;
  const uint16_t* wproj_pk = ws + WPROJ_PK;
  const uint16_t* kvbuf    = ws + KVBUF;

  // ---------- Q projection ----------
  f32x4 qacc[4][4] = {};
  for (int kt = 0; kt < 8; ++kt){
    __syncthreads();
    { // stage x K-slice (f32 -> bf16)
      const int rr = t >> 2, kk = (t & 3) * 8;
      const int bh = rr >> 6, n = rr & 63;
      u16x8 v = {};
      if (n < 49){
        const float* src = x + ((size_t)(b0 + bh) * 49 + n) * 256 + kt * 32 + kk;
        #pragma unroll
        for (int jj = 0; jj < 8; ++jj) v[jj] = f2bf(src[jj]);
      }
      *reinterpret_cast<u16x8*>(smem + XS + ((rr * 64 + kk * 2) ^ ((rr & 7) << 4))) = v;
    }
    #pragma unroll
    for (int rep = 0; rep < 2; ++rep){ // stage wq B-frags
      const int fg = t + rep * 512;
      const int nt = fg >> 6, l2 = fg & 63;
      *reinterpret_cast<u16x8*>(smem + BS + fg * 16) =
        *reinterpret_cast<const u16x8*>(wq_pk + (size_t)((nt * 8 + kt) * 64 + l2) * 8);
    }
    __syncthreads();
    #pragma unroll
    for (int mt = 0; mt < 4; ++mt){
      const int row = gm * 64 + mt * 16 + (lane & 15);
      bf16x8 a = *reinterpret_cast<const bf16x8*>(smem + XS + ((row * 64 + (lane >> 4) * 16) ^ ((row & 7) << 4)));
      #pragma unroll
      for (int nt = 0; nt < 4; ++nt){
        bf16x8 bfr = *reinterpret_cast<const bf16x8*>(smem + BS + ((gn * 4 + nt) * 64 + lane) * 16);
        qacc[mt][nt] = __builtin_amdgcn_mfma_f32_16x16x32_bf16(a, bfr, qacc[mt][nt], 0, 0, 0);
      }
    }
  }
  __syncthreads();
  // q -> OS (bf16, +bq, *scale)
  #pragma unroll
  for (int nt = 0; nt < 4; ++nt){
    const int col = gn * 64 + nt * 16 + (lane & 15);
    const float bqv = bq[col];
    #pragma unroll
    for (int mt = 0; mt < 4; ++mt){
      const int rb = gm * 64 + mt * 16 + (lane >> 4) * 4;
      #pragma unroll
      for (int i = 0; i < 4; ++i){
        const int row = rb + i;
        *reinterpret_cast<uint16_t*>(smem + OS + ((row * 512 + col * 2) ^ ((row & 7) << 4)))
          = f2bf((qacc[mt][nt][i] + bqv) * SCALE_Q);
      }
    }
  }

  // ---------- attention (wave w == head w) ----------
  for (int bh = 0; bh < 2; ++bh){
    __syncthreads();
    { // zero K/V staging (covers pad rows 21..31)
      u16x8 z = {};
      #pragma unroll
      for (int rep = 0; rep < 4; ++rep)
        *reinterpret_cast<u16x8*>(smem + KS + (t + rep * 512) * 16) = z;
    }
    __syncthreads();
    for (int fg = t; fg < 1344; fg += 512){ // stage kv for this batch
      const int dch = (fg & 3) * 8;
      const int m = (fg >> 2) % 21;
      const int hh = (fg / 84) & 7;
      const int kind = fg / 672;
      const uint16_t* src = kvbuf + ((((size_t)(b0 + bh) * 2 + kind) * 8 + hh) * 21 + m) * 32 + dch;
      if (kind == 0){
        *reinterpret_cast<u16x8*>(smem + KS + (((hh * 32 + m) * 64 + dch * 2) ^ ((m & 7) << 4)))
          = *reinterpret_cast<const u16x8*>(src);
      } else {
        #pragma unroll
        for (int jj = 0; jj < 8; ++jj){
          const int d = dch + jj;
          *reinterpret_cast<uint16_t*>(smem + VT + (((hh * 32 + d) * 64 + m * 2) ^ ((d & 7) << 4))) = src[jj];
        }
      }
    }
    __syncthreads();
    // scores = q @ K^T   (M=64 rows, N=32 kv slots, K=32 dims)
    f32x4 sacc[4][2];
    #pragma unroll
    for (int mt = 0; mt < 4; ++mt){
      const int row = bh * 64 + mt * 16 + (lane & 15);
      bf16x8 a = *reinterpret_cast<const bf16x8*>(smem + OS + ((row * 512 + w * 64 + (lane >> 4) * 16) ^ ((row & 7) << 4)));
      #pragma unroll
      for (int nt = 0; nt < 2; ++nt){
        const int m0 = nt * 16 + (lane & 15);
        bf16x8 bfr = *reinterpret_cast<const bf16x8*>(smem + KS + (((w * 32 + m0) * 64 + (lane >> 4) * 16) ^ ((m0 & 7) << 4)));
        f32x4 z = {};
        sacc[mt][nt] = __builtin_amdgcn_mfma_f32_16x16x32_bf16(a, bfr, z, 0, 0, 0);
      }
    }
    // softmax over 21 valid kv slots, in C-fragment layout; write P -> PA
    const bool ok1 = (lane & 15) < 5;  // col 16+(lane&15) < 21
    #pragma unroll
    for (int mt = 0; mt < 4; ++mt){
      #pragma unroll
      for (int i = 0; i < 4; ++i){
        const float s0 = sacc[mt][0][i];
        const float s1 = sacc[mt][1][i];
        float mx = fmaxf(s0, ok1 ? s1 : -3.0e38f);
        #pragma unroll
        for (int dd = 1; dd < 16; dd <<= 1) mx = fmaxf(mx, __shfl_xor(mx, dd));
        const float e0 = __expf(s0 - mx);
        const float e1 = ok1 ? __expf(s1 - mx) : 0.f;
        float sm = e0 + e1;
        #pragma unroll
        for (int dd = 1; dd < 16; dd <<= 1) sm += __shfl_xor(sm, dd);
        const float inv = 1.0f / sm;
        const int row = mt * 16 + (lane >> 4) * 4 + i;
        const int c0 = lane & 15;
        *reinterpret_cast<uint16_t*>(smem + PA + (((w * 64 + row) * 64 + c0 * 2) ^ ((row & 7) << 4))) = f2bf(e0 * inv);
        *reinterpret_cast<uint16_t*>(smem + PA + (((w * 64 + row) * 64 + (c0 + 16) * 2) ^ ((row & 7) << 4))) = f2bf(e1 * inv);
      }
    }
    __syncthreads();
    // O = P @ V  (M=64 rows, N=32 dims, K=32 kv slots; pads are zero)
    f32x4 oacc[4][2];
    #pragma unroll
    for (int mt = 0; mt < 4; ++mt){
      const int prow = mt * 16 + (lane & 15);
      bf16x8 a = *reinterpret_cast<const bf16x8*>(smem + PA + (((w * 64 + prow) * 64 + (lane >> 4) * 16) ^ ((prow & 7) << 4)));
      #pragma unroll
      for (int nt = 0; nt < 2; ++nt){
        const int d0 = nt * 16 + (lane & 15);
        bf16x8 bfr = *reinterpret_cast<const bf16x8*>(smem + VT + (((w * 32 + d0) * 64 + (lane >> 4) * 16) ^ ((d0 & 7) << 4)));
        f32x4 z = {};
        oacc[mt][nt] = __builtin_amdgcn_mfma_f32_16x16x32_bf16(a, bfr, z, 0, 0, 0);
      }
    }
    // O -> OS (overwrites q of this batch, own column slice only)
    #pragma unroll
    for (int mt = 0; mt < 4; ++mt)
    #pragma unroll
    for (int nt = 0; nt < 2; ++nt)
    #pragma unroll
    for (int i = 0; i < 4; ++i){
      const int row = bh * 64 + mt * 16 + (lane >> 4) * 4 + i;
      const int col = w * 32 + nt * 16 + (lane & 15);
      *reinterpret_cast<uint16_t*>(smem + OS + ((row * 512 + col * 2) ^ ((row & 7) << 4))) = f2bf(oacc[mt][nt][i]);
    }
  }

  __syncthreads();
  // ---------- out projection ----------
  f32x4 pacc[4][4] = {};
  for (int kt = 0; kt < 8; ++kt){
    __syncthreads();
    #pragma unroll
    for (int rep = 0; rep < 2; ++rep){ // stage wproj B-frags
      const int fg = t + rep * 512;
      const int nt = fg >> 6, l2 = fg & 63;
      *reinterpret_cast<u16x8*>(smem + BS + fg * 16) =
        *reinterpret_cast<const u16x8*>(wproj_pk + (size_t)((nt * 8 + kt) * 64 + l2) * 8);
    }
    __syncthreads();
    #pragma unroll
    for (int mt = 0; mt < 4; ++mt){
      const int row = gm * 64 + mt * 16 + (lane & 15);
      bf16x8 a = *reinterpret_cast<const bf16x8*>(smem + OS + ((row * 512 + kt * 64 + (lane >> 4) * 16) ^ ((row & 7) << 4)));
      #pragma unroll
      for (int nt = 0; nt < 4; ++nt){
        bf16x8 bfr = *reinterpret_cast<const bf16x8*>(smem + BS + ((gn * 4 + nt) * 64 + lane) * 16);
        pacc[mt][nt] = __builtin_amdgcn_mfma_f32_16x16x32_bf16(a, bfr, pacc[mt][nt], 0, 0, 0);
      }
    }
  }
  #pragma unroll
  for (int nt = 0; nt < 4; ++nt){
    const int col = gn * 64 + nt * 16 + (lane & 15);
    const float bpv = bproj[col];
    #pragma unroll
    for (int mt = 0; mt < 4; ++mt){
      const int nb = mt * 16 + (lane >> 4) * 4;
      #pragma unroll
      for (int i = 0; i < 4; ++i){
        const int n = nb + i;
        if (n < 49)
          out[((size_t)(b0 + gm) * 49 + n) * 256 + col] = pacc[mt][nt][i] + bpv;
      }
    }
  }
}

// ---------------------------------------------------------------------------
extern "C" void kernel_launch(void* const* d_in, const int* in_sizes, int n_in,
                              void* d_out, int out_size, void* d_ws, size_t ws_size,
                              hipStream_t stream)
{
  const float* x     = (const float*)d_in[0];
  const float* wq    = (const float*)d_in[1];
  const float* bq    = (const float*)d_in[2];
  const float* wd1   = (const float*)d_in[3];
  const float* bd1   = (const float*)d_in[4];
  const float* wp1   = (const float*)d_in[5];
  const float* bp1   = (const float*)d_in[6];
  const float* wd2   = (const float*)d_in[7];
  const float* bd2   = (const float*)d_in[8];
  const float* wp2   = (const float*)d_in[9];
  const float* bp2   = (const float*)d_in[10];
  const float* wd3   = (const float*)d_in[11];
  const float* bd3   = (const float*)d_in[12];
  const float* wp3   = (const float*)d_in[13];
  const float* bp3   = (const float*)d_in[14];
  const float* wd4   = (const float*)d_in[15];
  const float* bd4   = (const float*)d_in[16];
  const float* wp4   = (const float*)d_in[17];
  const float* bp4   = (const float*)d_in[18];
  const float* wproj = (const float*)d_in[19];
  const float* bproj = (const float*)d_in[20];
  uint16_t* ws = (uint16_t*)d_ws;
  float* out = (float*)d_out;

  k_prepack<<<320, 256, 0, stream>>>(wq, wp1, wp2, wp3, wp4, wproj, ws);
  k_kv<<<512, 512, 86016, stream>>>(x, wd1, bd1, bp1, wd2, bd2, bp2,
                                    wd3, bd3, bp3, wd4, bd4, bp4,
                                    ws, ws + KVBUF);
  k_attn<<<2048, 512, 155648, stream>>>(x, bq, bproj, ws, out);
}

// Round 2
// 398.400 us; speedup vs baseline: 1.0284x; 1.0284x over previous
//
#include <hip/hip_runtime.h>
#include <stdint.h>

typedef __attribute__((ext_vector_type(8))) short bf16x8;
typedef __attribute__((ext_vector_type(8))) unsigned short u16x8;
typedef __attribute__((ext_vector_type(4))) float f32x4;

#define DEV __device__ __forceinline__

// ws layout in ushort elements
constexpr size_t WQ_PK    = 0;         // 65536 elems
constexpr size_t WPROJ_PK = 65536;     // 65536 elems
constexpr size_t WP_PK    = 131072;    // 4 * 131072 elems
constexpr size_t KVBUF    = 655360;    // 4096*2*8*21*32 = 44040192 elems

constexpr float SCALE_Q = 0.17677669529663687f;  // 32^-0.5

DEV uint16_t f2bf(float f){
  uint32_t u = __builtin_bit_cast(uint32_t, f);
  u += 0x7fffu + ((u >> 16) & 1u);
  return (uint16_t)(u >> 16);
}

// ---------------------------------------------------------------------------
// K0: prepack weights into MFMA B-fragment layout, f32 -> bf16.
// B-frag for (nt,kt): lane l, j=0..7 supplies B[k=kt*32+(l>>4)*8+j][n=nt*16+(l&15)]
// = W[n][k].  Stored at pk[((nt*8+kt)*64+l)*8 + j].
// ---------------------------------------------------------------------------
__global__ __launch_bounds__(256) void k_prepack(
    const float* __restrict__ wq,  const float* __restrict__ wp1,
    const float* __restrict__ wp2, const float* __restrict__ wp3,
    const float* __restrict__ wp4, const float* __restrict__ wproj,
    uint16_t* __restrict__ ws)
{
  int f = blockIdx.x * 256 + threadIdx.x;   // 0..81919 fragment id
  const float* src; uint16_t* dst; int g;
  if (f < 8192)       { src = wq;    dst = ws + WQ_PK;    g = f; }
  else if (f < 16384) { src = wproj; dst = ws + WPROJ_PK; g = f - 8192; }
  else {
    int j = (f - 16384) >> 14;
    src = j == 0 ? wp1 : j == 1 ? wp2 : j == 2 ? wp3 : wp4;
    dst = ws + WP_PK + (size_t)j * 131072;
    g = (f - 16384) & 16383;
  }
  int l = g & 63, kt = (g >> 6) & 7, nt = g >> 9;
  int n  = nt * 16 + (l & 15);
  int k0 = kt * 32 + (l >> 4) * 8;
  const float* s = src + (size_t)n * 256 + k0;
  u16x8 v;
  #pragma unroll
  for (int j = 0; j < 8; ++j) v[j] = f2bf(s[j]);
  *reinterpret_cast<u16x8*>(dst + (size_t)g * 8) = v;
}

// ---------------------------------------------------------------------------
// K1: depthwise convs + pointwise (MFMA) + gather -> kv buffer (bf16).
// 4 batches per block, 512 threads (8 waves). LDS 43008 B.
// abuf [84][256] ushort, swizzled: byte = (row*512 + c*2) ^ ((row&7)<<4)
// ---------------------------------------------------------------------------
__global__ __launch_bounds__(512, 3) void k_kv(
    const float* __restrict__ x,
    const float* __restrict__ wd1, const float* __restrict__ bd1, const float* __restrict__ bp1,
    const float* __restrict__ wd2, const float* __restrict__ bd2, const float* __restrict__ bp2,
    const float* __restrict__ wd3, const float* __restrict__ bd3, const float* __restrict__ bp3,
    const float* __restrict__ wd4, const float* __restrict__ bd4, const float* __restrict__ bp4,
    const uint16_t* __restrict__ ws, uint16_t* __restrict__ kvbuf)
{
  extern __shared__ char smem[];  // 43008 B
  const int t = threadIdx.x, lane = t & 63, w = t >> 6;
  const int b0 = blockIdx.x * 4;

  constexpr int DILA[4] = {1,2,3,4}, PADA[4] = {0,0,1,2}, OWA[4] = {3,2,2,2};
  constexpr int HWA[4]  = {9,4,4,4}, OFFA[4] = {0,9,13,17}, MTA[4] = {3,1,1,1};

  // ---- depthwise conv, all branches; write dT (bf16) to LDS ----
  {
    const int c = t & 255, half = t >> 8;
    for (int pass = 0; pass < 2; ++pass){
      const int bh = pass * 2 + half;
      float xr[49];
      #pragma unroll
      for (int p = 0; p < 49; ++p)
        xr[p] = x[((size_t)(b0 + bh) * 49 + p) * 256 + c];
      #pragma unroll
      for (int j = 0; j < 4; ++j){
        const float* wdp = j==0?wd1:j==1?wd2:j==2?wd3:wd4;
        const float* bdp = j==0?bd1:j==1?bd2:j==2?bd3:bd4;
        float wv[9];
        #pragma unroll
        for (int q = 0; q < 9; ++q) wv[q] = wdp[c * 9 + q];
        const float bdv = bdp[c];
        #pragma unroll
        for (int oy = 0; oy < OWA[j]; ++oy)
        #pragma unroll
        for (int ox = 0; ox < OWA[j]; ++ox){
          float acc = bdv;
          #pragma unroll
          for (int ky = 0; ky < 3; ++ky){
            const int yy = oy * 2 - PADA[j] + ky * DILA[j];
            if (yy < 0 || yy > 6) continue;
            #pragma unroll
            for (int kx = 0; kx < 3; ++kx){
              const int xx = ox * 2 - PADA[j] + kx * DILA[j];
              if (xx < 0 || xx > 6) continue;
              acc += xr[yy * 7 + xx] * wv[ky * 3 + kx];
            }
          }
          const int row = bh * 21 + OFFA[j] + oy * OWA[j] + ox;
          *reinterpret_cast<uint16_t*>(smem + ((row * 512 + c * 2) ^ ((row & 7) << 4))) = f2bf(acc);
        }
      }
    }
  }
  __syncthreads();

  // ---- pointwise GEMM per branch + gather-write ----
  // wave w owns output cols [w*64, w*64+64)
  #pragma unroll
  for (int j = 0; j < 4; ++j){
    const uint16_t* pk = ws + WP_PK + (size_t)j * 131072;
    const float* bpp = j==0?bp1:j==1?bp2:j==2?bp3:bp4;
    const int hw = HWA[j], off = OFFA[j], MV = hw * 4;
    for (int mt = 0; mt < MTA[j]; ++mt){
      f32x4 acc[4] = {};
      const int mrow = mt * 16 + (lane & 15);
      const bool av = mrow < MV;
      const int bh = mrow / hw, s = mrow - bh * hw;
      const int arow = bh * 21 + off + s;
      const int abase = arow * 512 + (lane >> 4) * 16;
      #pragma unroll
      for (int kt = 0; kt < 8; ++kt){
        bf16x8 a = {};
        if (av) a = *reinterpret_cast<const bf16x8*>(smem + ((abase + kt * 64) ^ ((arow & 7) << 4)));
        #pragma unroll
        for (int nt = 0; nt < 4; ++nt){
          const int ntg = w * 4 + nt;
          bf16x8 bfr = *reinterpret_cast<const bf16x8*>(pk + (size_t)((ntg * 8 + kt) * 64 + lane) * 8);
          acc[nt] = __builtin_amdgcn_mfma_f32_16x16x32_bf16(a, bfr, acc[nt], 0, 0, 0);
        }
      }
      const int mr2 = mt * 16 + (lane >> 4) * 4;
      #pragma unroll
      for (int nt = 0; nt < 4; ++nt){
        const int o = w * 64 + nt * 16 + (lane & 15);
        const float bpv = bpp[o];
        const int r = o >> 1, e = o & 1, hh = r >> 5, d = r & 31;
        #pragma unroll
        for (int i = 0; i < 4; ++i){
          const int m = mr2 + i;
          if (m >= MV) continue;
          const int bh2 = m / hw, s2 = m - bh2 * hw;
          const int c2 = e * hw + s2, kind = c2 & 1, mg = off + (c2 >> 1);
          const float val = acc[nt][i] + bpv;
          kvbuf[((((size_t)(b0 + bh2) * 2 + kind) * 8 + hh) * 21 + mg) * 32 + d] = f2bf(val);
        }
      }
    }
  }
}

// ---------------------------------------------------------------------------
// K2: fused q-proj + attention + out-proj. 1 batch/block, 512 threads (8
// waves), LDS 64 KB -> 2 blocks/CU. Weights (B-frags) read from global (L2).
// Region R0 [0,32768): x bf16 [64][256] swz; reused per attention pass:
//   KS 4x2KB @0, VT 4x2KB @8192, PA 4x4KB @16384.
// Region R1 [32768,65536): q/O buffer [64][256] us swz.
// GEMMs: wave w -> cols [32w,32w+32). Attention: pass p, head p*4+(w>>1),
// row half (w&1)*32.
// ---------------------------------------------------------------------------
__global__ __launch_bounds__(512, 4) void k_attn(
    const float* __restrict__ x, const float* __restrict__ bq,
    const float* __restrict__ bproj, const uint16_t* __restrict__ ws,
    float* __restrict__ out)
{
  extern __shared__ char smem[];   // 65536 B
  constexpr int OSB = 32768;
  const int t = threadIdx.x, lane = t & 63, w = t >> 6;
  const size_t b = blockIdx.x;
  const uint16_t* wq_pk    = ws + WQ_PK;
  const uint16_t* wproj_pk = ws + WPROJ_PK;
  const uint16_t* kvbuf    = ws + KVBUF;

  // ---- stage x -> bf16 [64][256] swz (rows >=49 zeroed) ----
  {
    const int r = t >> 3, c0 = (t & 7) * 32;
    u16x8 vv[4] = {};
    if (r < 49){
      const float* src = x + (b * 49 + r) * 256 + c0;
      #pragma unroll
      for (int jj = 0; jj < 4; ++jj)
        #pragma unroll
        for (int k2 = 0; k2 < 8; ++k2) vv[jj][k2] = f2bf(src[jj * 8 + k2]);
    }
    #pragma unroll
    for (int jj = 0; jj < 4; ++jj)
      *reinterpret_cast<u16x8*>(smem + ((r * 512 + c0 * 2 + jj * 16) ^ ((r & 7) << 4))) = vv[jj];
  }
  __syncthreads();

  // ---- q-proj (no barriers; B-frags from global) ----
  f32x4 qacc[4][2] = {};
  #pragma unroll 2
  for (int kt = 0; kt < 8; ++kt){
    bf16x8 a[4];
    #pragma unroll
    for (int mt = 0; mt < 4; ++mt){
      const int row = mt * 16 + (lane & 15);
      a[mt] = *reinterpret_cast<const bf16x8*>(smem + ((row * 512 + kt * 64 + (lane >> 4) * 16) ^ ((row & 7) << 4)));
    }
    #pragma unroll
    for (int nt = 0; nt < 2; ++nt){
      bf16x8 bfr = *reinterpret_cast<const bf16x8*>(wq_pk + (size_t)(((w * 2 + nt) * 8 + kt) * 64 + lane) * 8);
      #pragma unroll
      for (int mt = 0; mt < 4; ++mt)
        qacc[mt][nt] = __builtin_amdgcn_mfma_f32_16x16x32_bf16(a[mt], bfr, qacc[mt][nt], 0, 0, 0);
    }
  }
  // q (bias+scale, bf16) -> R1
  #pragma unroll
  for (int nt = 0; nt < 2; ++nt){
    const int col = w * 32 + nt * 16 + (lane & 15);
    const float bqv = bq[col];
    #pragma unroll
    for (int mt = 0; mt < 4; ++mt)
      #pragma unroll
      for (int i = 0; i < 4; ++i){
        const int row = mt * 16 + (lane >> 4) * 4 + i;
        *reinterpret_cast<uint16_t*>(smem + OSB + ((row * 512 + col * 2) ^ ((row & 7) << 4)))
          = f2bf((qacc[mt][nt][i] + bqv) * SCALE_Q);
      }
  }
  __syncthreads();

  // ---- attention: 2 passes x 4 heads, 2 waves/head ----
  for (int p = 0; p < 2; ++p){
    { // stage K (swz by slot) and V^T (swz by dim); V pads zeroed, K pads masked later
      const int sh4 = t >> 7, m = (t >> 2) & 31, dch = (t & 3) * 8;
      const int h = p * 4 + sh4;
      u16x8 kf = {}, vf = {};
      if (m < 21){
        kf = *reinterpret_cast<const u16x8*>(kvbuf + (((b * 2 + 0) * 8 + h) * 21 + m) * 32 + dch);
        vf = *reinterpret_cast<const u16x8*>(kvbuf + (((b * 2 + 1) * 8 + h) * 21 + m) * 32 + dch);
      }
      *reinterpret_cast<u16x8*>(smem + sh4 * 2048 + ((m * 64 + dch * 2) ^ ((m & 7) << 4))) = kf;
      #pragma unroll
      for (int jj = 0; jj < 8; ++jj){
        const int d = dch + jj;
        *reinterpret_cast<uint16_t*>(smem + 8192 + sh4 * 2048 + ((d * 64 + m * 2) ^ ((d & 7) << 4))) = vf[jj];
      }
    }
    __syncthreads();

    const int h4 = w >> 1, wh = w & 1;
    const int hcol = (p * 4 + h4) * 64;   // byte col offset of this head in R1
    const int pabase = 16384 + h4 * 4096;

    // scores: M=32 rows (2 mt), N=32 slots (2 nt), K=32 dims
    bf16x8 bk[2];
    #pragma unroll
    for (int nt = 0; nt < 2; ++nt){
      const int m0 = nt * 16 + (lane & 15);
      bk[nt] = *reinterpret_cast<const bf16x8*>(smem + h4 * 2048 + ((m0 * 64 + (lane >> 4) * 16) ^ ((m0 & 7) << 4)));
    }
    f32x4 sacc[2][2];
    #pragma unroll
    for (int mt = 0; mt < 2; ++mt){
      const int row = wh * 32 + mt * 16 + (lane & 15);
      bf16x8 aq = *reinterpret_cast<const bf16x8*>(smem + OSB + ((row * 512 + hcol + (lane >> 4) * 16) ^ ((row & 7) << 4)));
      #pragma unroll
      for (int nt = 0; nt < 2; ++nt){
        f32x4 z = {};
        sacc[mt][nt] = __builtin_amdgcn_mfma_f32_16x16x32_bf16(aq, bk[nt], z, 0, 0, 0);
      }
    }
    // softmax (21 valid slots) in C-frag layout; P -> PA (pads written 0)
    const bool ok1 = (lane & 15) < 5;
    #pragma unroll
    for (int mt = 0; mt < 2; ++mt)
      #pragma unroll
      for (int i = 0; i < 4; ++i){
        const float s0 = sacc[mt][0][i];
        const float s1 = sacc[mt][1][i];
        float mx = fmaxf(s0, ok1 ? s1 : -3.0e38f);
        #pragma unroll
        for (int dd = 1; dd < 16; dd <<= 1) mx = fmaxf(mx, __shfl_xor(mx, dd));
        const float e0 = __expf(s0 - mx);
        const float e1 = ok1 ? __expf(s1 - mx) : 0.f;
        float sm = e0 + e1;
        #pragma unroll
        for (int dd = 1; dd < 16; dd <<= 1) sm += __shfl_xor(sm, dd);
        const float inv = 1.0f / sm;
        const int pr = wh * 32 + mt * 16 + (lane >> 4) * 4 + i;
        const int c0 = lane & 15;
        *reinterpret_cast<uint16_t*>(smem + pabase + ((pr * 64 + c0 * 2) ^ ((pr & 7) << 4))) = f2bf(e0 * inv);
        *reinterpret_cast<uint16_t*>(smem + pabase + ((pr * 64 + (c0 + 16) * 2) ^ ((pr & 7) << 4))) = f2bf(e1 * inv);
      }
    // PV (produce/consume within wave; no barrier): M=32 rows, N=32 dims, K=32 slots
    f32x4 oacc[2][2];
    #pragma unroll
    for (int mt = 0; mt < 2; ++mt){
      const int pr = wh * 32 + mt * 16 + (lane & 15);
      bf16x8 ap = *reinterpret_cast<const bf16x8*>(smem + pabase + ((pr * 64 + (lane >> 4) * 16) ^ ((pr & 7) << 4)));
      #pragma unroll
      for (int nt = 0; nt < 2; ++nt){
        const int d0 = nt * 16 + (lane & 15);
        bf16x8 bv = *reinterpret_cast<const bf16x8*>(smem + 8192 + h4 * 2048 + ((d0 * 64 + (lane >> 4) * 16) ^ ((d0 & 7) << 4)));
        f32x4 z = {};
        oacc[mt][nt] = __builtin_amdgcn_mfma_f32_16x16x32_bf16(ap, bv, z, 0, 0, 0);
      }
    }
    // O -> R1 (own head cols)
    #pragma unroll
    for (int mt = 0; mt < 2; ++mt)
      #pragma unroll
      for (int nt = 0; nt < 2; ++nt)
        #pragma unroll
        for (int i = 0; i < 4; ++i){
          const int row = wh * 32 + mt * 16 + (lane >> 4) * 4 + i;
          const int colb = hcol + (nt * 16 + (lane & 15)) * 2;
          *reinterpret_cast<uint16_t*>(smem + OSB + ((row * 512 + colb) ^ ((row & 7) << 4))) = f2bf(oacc[mt][nt][i]);
        }
    __syncthreads();
  }

  // ---- out-proj (no barriers; B-frags from global) ----
  f32x4 pacc[4][2] = {};
  #pragma unroll 2
  for (int kt = 0; kt < 8; ++kt){
    bf16x8 a[4];
    #pragma unroll
    for (int mt = 0; mt < 4; ++mt){
      const int row = mt * 16 + (lane & 15);
      a[mt] = *reinterpret_cast<const bf16x8*>(smem + OSB + ((row * 512 + kt * 64 + (lane >> 4) * 16) ^ ((row & 7) << 4)));
    }
    #pragma unroll
    for (int nt = 0; nt < 2; ++nt){
      bf16x8 bfr = *reinterpret_cast<const bf16x8*>(wproj_pk + (size_t)(((w * 2 + nt) * 8 + kt) * 64 + lane) * 8);
      #pragma unroll
      for (int mt = 0; mt < 4; ++mt)
        pacc[mt][nt] = __builtin_amdgcn_mfma_f32_16x16x32_bf16(a[mt], bfr, pacc[mt][nt], 0, 0, 0);
    }
  }
  #pragma unroll
  for (int nt = 0; nt < 2; ++nt){
    const int col = w * 32 + nt * 16 + (lane & 15);
    const float bpv = bproj[col];
    #pragma unroll
    for (int mt = 0; mt < 4; ++mt)
      #pragma unroll
      for (int i = 0; i < 4; ++i){
        const int n = mt * 16 + (lane >> 4) * 4 + i;
        if (n < 49)
          out[(b * 49 + n) * 256 + col] = pacc[mt][nt][i] + bpv;
      }
  }
}

// ---------------------------------------------------------------------------
extern "C" void kernel_launch(void* const* d_in, const int* in_sizes, int n_in,
                              void* d_out, int out_size, void* d_ws, size_t ws_size,
                              hipStream_t stream)
{
  const float* x     = (const float*)d_in[0];
  const float* wq    = (const float*)d_in[1];
  const float* bq    = (const float*)d_in[2];
  const float* wd1   = (const float*)d_in[3];
  const float* bd1   = (const float*)d_in[4];
  const float* wp1   = (const float*)d_in[5];
  const float* bp1   = (const float*)d_in[6];
  const float* wd2   = (const float*)d_in[7];
  const float* bd2   = (const float*)d_in[8];
  const float* wp2   = (const float*)d_in[9];
  const float* bp2   = (const float*)d_in[10];
  const float* wd3   = (const float*)d_in[11];
  const float* bd3   = (const float*)d_in[12];
  const float* wp3   = (const float*)d_in[13];
  const float* bp3   = (const float*)d_in[14];
  const float* wd4   = (const float*)d_in[15];
  const float* bd4   = (const float*)d_in[16];
  const float* wp4   = (const float*)d_in[17];
  const float* bp4   = (const float*)d_in[18];
  const float* wproj = (const float*)d_in[19];
  const float* bproj = (const float*)d_in[20];
  uint16_t* ws = (uint16_t*)d_ws;
  float* out = (float*)d_out;

  k_prepack<<<320, 256, 0, stream>>>(wq, wp1, wp2, wp3, wp4, wproj, ws);
  k_kv<<<1024, 512, 43008, stream>>>(x, wd1, bd1, bp1, wd2, bd2, bp2,
                                     wd3, bd3, bp3, wd4, bd4, bp4,
                                     ws, ws + KVBUF);
  k_attn<<<4096, 512, 65536, stream>>>(x, bq, bproj, ws, out);
}

// Round 3
// 314.022 us; speedup vs baseline: 1.3047x; 1.2687x over previous
//
#include <hip/hip_runtime.h>
#include <stdint.h>

typedef __attribute__((ext_vector_type(8))) short bf16x8;
typedef __attribute__((ext_vector_type(8))) unsigned short u16x8;
typedef __attribute__((ext_vector_type(4))) float f32x4;

#define DEV __device__ __forceinline__

// ws layout in ushort elements
constexpr size_t WQ_PK    = 0;         // 65536 elems
constexpr size_t WPROJ_PK = 65536;     // 65536 elems
constexpr size_t WP_PK    = 131072;    // 4 * 131072 elems
constexpr size_t KVBUF    = 655360;    // 4096*21*512 = 44040192 elems
// kvbuf layout: [b][row 0..20 (concat spatial)][o 0..511] bf16 — producer-
// coalesced. Gather permute to (kind,head,slot,dim) happens in k_attn staging.

constexpr float SCALE_Q = 0.17677669529663687f;  // 32^-0.5

DEV uint16_t f2bf(float f){
  uint32_t u = __builtin_bit_cast(uint32_t, f);
  u += 0x7fffu + ((u >> 16) & 1u);
  return (uint16_t)(u >> 16);
}

// ---------------------------------------------------------------------------
// K0: prepack weights into MFMA B-fragment layout, f32 -> bf16.
// ---------------------------------------------------------------------------
__global__ __launch_bounds__(256) void k_prepack(
    const float* __restrict__ wq,  const float* __restrict__ wp1,
    const float* __restrict__ wp2, const float* __restrict__ wp3,
    const float* __restrict__ wp4, const float* __restrict__ wproj,
    uint16_t* __restrict__ ws)
{
  int f = blockIdx.x * 256 + threadIdx.x;   // 0..81919 fragment id
  const float* src; uint16_t* dst; int g;
  if (f < 8192)       { src = wq;    dst = ws + WQ_PK;    g = f; }
  else if (f < 16384) { src = wproj; dst = ws + WPROJ_PK; g = f - 8192; }
  else {
    int j = (f - 16384) >> 14;
    src = j == 0 ? wp1 : j == 1 ? wp2 : j == 2 ? wp3 : wp4;
    dst = ws + WP_PK + (size_t)j * 131072;
    g = (f - 16384) & 16383;
  }
  int l = g & 63, kt = (g >> 6) & 7, nt = g >> 9;
  int n  = nt * 16 + (l & 15);
  int k0 = kt * 32 + (l >> 4) * 8;
  const float* s = src + (size_t)n * 256 + k0;
  u16x8 v;
  #pragma unroll
  for (int j = 0; j < 8; ++j) v[j] = f2bf(s[j]);
  *reinterpret_cast<u16x8*>(dst + (size_t)g * 8) = v;
}

// ---------------------------------------------------------------------------
// K1: depthwise convs + pointwise (MFMA) -> kvbuf2[b][row][o] (bf16).
// 8 batches per block, 512 threads (8 waves). LDS 86016 B.
// dT [168][256] ushort, swizzled: byte = (row*512 + c*2) ^ ((row&7)<<4)
// ---------------------------------------------------------------------------
__global__ __launch_bounds__(512, 2) void k_kv(
    const float* __restrict__ x,
    const float* __restrict__ wd1, const float* __restrict__ bd1, const float* __restrict__ bp1,
    const float* __restrict__ wd2, const float* __restrict__ bd2, const float* __restrict__ bp2,
    const float* __restrict__ wd3, const float* __restrict__ bd3, const float* __restrict__ bp3,
    const float* __restrict__ wd4, const float* __restrict__ bd4, const float* __restrict__ bp4,
    const uint16_t* __restrict__ ws, uint16_t* __restrict__ kvbuf)
{
  extern __shared__ char smem[];  // 86016 B
  const int t = threadIdx.x, lane = t & 63, w = t >> 6;
  const int b0 = blockIdx.x * 8;

  constexpr int DILA[4] = {1,2,3,4}, PADA[4] = {0,0,1,2}, OWA[4] = {3,2,2,2};
  constexpr int HWA[4]  = {9,4,4,4}, OFFA[4] = {0,9,13,17}, MTA[4] = {5,2,2,2};

  // ---- depthwise conv, all branches; write dT (bf16) to LDS ----
  {
    const int c = t & 255, half = t >> 8;
    for (int pass = 0; pass < 4; ++pass){
      const int bh = pass * 2 + half;
      float xr[49];
      #pragma unroll
      for (int p = 0; p < 49; ++p)
        xr[p] = x[((size_t)(b0 + bh) * 49 + p) * 256 + c];
      #pragma unroll
      for (int j = 0; j < 4; ++j){
        const float* wdp = j==0?wd1:j==1?wd2:j==2?wd3:wd4;
        const float* bdp = j==0?bd1:j==1?bd2:j==2?bd3:bd4;
        float wv[9];
        #pragma unroll
        for (int q = 0; q < 9; ++q) wv[q] = wdp[c * 9 + q];
        const float bdv = bdp[c];
        #pragma unroll
        for (int oy = 0; oy < OWA[j]; ++oy)
        #pragma unroll
        for (int ox = 0; ox < OWA[j]; ++ox){
          float acc = bdv;
          #pragma unroll
          for (int ky = 0; ky < 3; ++ky){
            const int yy = oy * 2 - PADA[j] + ky * DILA[j];
            if (yy < 0 || yy > 6) continue;
            #pragma unroll
            for (int kx = 0; kx < 3; ++kx){
              const int xx = ox * 2 - PADA[j] + kx * DILA[j];
              if (xx < 0 || xx > 6) continue;
              acc += xr[yy * 7 + xx] * wv[ky * 3 + kx];
            }
          }
          const int row = bh * 21 + OFFA[j] + oy * OWA[j] + ox;
          *reinterpret_cast<uint16_t*>(smem + ((row * 512 + c * 2) ^ ((row & 7) << 4))) = f2bf(acc);
        }
      }
    }
  }
  __syncthreads();

  // ---- pointwise GEMM per branch; coalesced write to kvbuf2[b][row][o] ----
  // wave w owns output cols [w*64, w*64+64)
  #pragma unroll
  for (int j = 0; j < 4; ++j){
    const uint16_t* pk = ws + WP_PK + (size_t)j * 131072;
    const float* bpp = j==0?bp1:j==1?bp2:j==2?bp3:bp4;
    const int hw = HWA[j], off = OFFA[j], MV = hw * 8;
    float bpv[4];
    #pragma unroll
    for (int nt = 0; nt < 4; ++nt) bpv[nt] = bpp[w * 64 + nt * 16 + (lane & 15)];
    for (int mt = 0; mt < MTA[j]; ++mt){
      f32x4 acc[4] = {};
      const int mrow = mt * 16 + (lane & 15);
      const bool av = mrow < MV;
      const int bh = mrow / hw, s = mrow - bh * hw;
      const int arow = bh * 21 + off + s;
      const int abase = arow * 512 + (lane >> 4) * 16;
      #pragma unroll
      for (int kt = 0; kt < 8; ++kt){
        bf16x8 a = {};
        if (av) a = *reinterpret_cast<const bf16x8*>(smem + ((abase + kt * 64) ^ ((arow & 7) << 4)));
        #pragma unroll
        for (int nt = 0; nt < 4; ++nt){
          const int ntg = w * 4 + nt;
          bf16x8 bfr = *reinterpret_cast<const bf16x8*>(pk + (size_t)((ntg * 8 + kt) * 64 + lane) * 8);
          acc[nt] = __builtin_amdgcn_mfma_f32_16x16x32_bf16(a, bfr, acc[nt], 0, 0, 0);
        }
      }
      const int mr2 = mt * 16 + (lane >> 4) * 4;
      #pragma unroll
      for (int i = 0; i < 4; ++i){
        const int m = mr2 + i;
        if (m >= MV) continue;
        const int bh2 = m / hw, s2 = m - bh2 * hw;
        const size_t grow = ((size_t)(b0 + bh2) * 21 + off + s2) * 512;
        #pragma unroll
        for (int nt = 0; nt < 4; ++nt)
          kvbuf[grow + w * 64 + nt * 16 + (lane & 15)] = f2bf(acc[nt][i] + bpv[nt]);
      }
    }
  }
}

// ---------------------------------------------------------------------------
// K2: fused q-proj + attention + out-proj. 1 batch/block, 512 threads (8
// waves), LDS 64 KB -> 2 blocks/CU. Weights (B-frags) read from global (L2).
// Region R0 [0,32768): x bf16 [64][256] swz; reused per attention pass:
//   KS 4x2KB @0, VT 4x2KB @8192, PA 4x4KB @16384.
// Region R1 [32768,65536): q/O buffer [64][256] us swz.
// ---------------------------------------------------------------------------
__global__ __launch_bounds__(512, 4) void k_attn(
    const float* __restrict__ x, const float* __restrict__ bq,
    const float* __restrict__ bproj, const uint16_t* __restrict__ ws,
    float* __restrict__ out)
{
  extern __shared__ char smem[];   // 65536 B
  constexpr int OSB = 32768;
  const int t = threadIdx.x, lane = t & 63, w = t >> 6;
  const size_t b = blockIdx.x;
  const uint16_t* wq_pk    = ws + WQ_PK;
  const uint16_t* wproj_pk = ws + WPROJ_PK;
  const uint16_t* kvbuf    = ws + KVBUF;

  // ---- stage x -> bf16 [64][256] swz (rows >=49 zeroed) ----
  {
    const int r = t >> 3, c0 = (t & 7) * 32;
    u16x8 vv[4] = {};
    if (r < 49){
      const float* src = x + (b * 49 + r) * 256 + c0;
      #pragma unroll
      for (int jj = 0; jj < 4; ++jj)
        #pragma unroll
        for (int k2 = 0; k2 < 8; ++k2) vv[jj][k2] = f2bf(src[jj * 8 + k2]);
    }
    #pragma unroll
    for (int jj = 0; jj < 4; ++jj)
      *reinterpret_cast<u16x8*>(smem + ((r * 512 + c0 * 2 + jj * 16) ^ ((r & 7) << 4))) = vv[jj];
  }
  __syncthreads();

  // ---- q-proj (no barriers; B-frags from global) ----
  f32x4 qacc[4][2] = {};
  #pragma unroll 2
  for (int kt = 0; kt < 8; ++kt){
    bf16x8 a[4];
    #pragma unroll
    for (int mt = 0; mt < 4; ++mt){
      const int row = mt * 16 + (lane & 15);
      a[mt] = *reinterpret_cast<const bf16x8*>(smem + ((row * 512 + kt * 64 + (lane >> 4) * 16) ^ ((row & 7) << 4)));
    }
    #pragma unroll
    for (int nt = 0; nt < 2; ++nt){
      bf16x8 bfr = *reinterpret_cast<const bf16x8*>(wq_pk + (size_t)(((w * 2 + nt) * 8 + kt) * 64 + lane) * 8);
      #pragma unroll
      for (int mt = 0; mt < 4; ++mt)
        qacc[mt][nt] = __builtin_amdgcn_mfma_f32_16x16x32_bf16(a[mt], bfr, qacc[mt][nt], 0, 0, 0);
    }
  }
  // q (bias+scale, bf16) -> R1
  #pragma unroll
  for (int nt = 0; nt < 2; ++nt){
    const int col = w * 32 + nt * 16 + (lane & 15);
    const float bqv = bq[col];
    #pragma unroll
    for (int mt = 0; mt < 4; ++mt)
      #pragma unroll
      for (int i = 0; i < 4; ++i){
        const int row = mt * 16 + (lane >> 4) * 4 + i;
        *reinterpret_cast<uint16_t*>(smem + OSB + ((row * 512 + col * 2) ^ ((row & 7) << 4)))
          = f2bf((qacc[mt][nt][i] + bqv) * SCALE_Q);
      }
  }
  __syncthreads();

  // ---- attention: 2 passes x 4 heads, 2 waves/head ----
  for (int p = 0; p < 2; ++p){
    { // stage K (swz by slot) and V^T (swz by dim) from kvbuf2 via inverse map
      const int sh4 = t >> 7, m = (t >> 2) & 31, dch = (t & 3) * 8;
      const int h = p * 4 + sh4;
      u16x8 kf = {}, vf = {};
      if (m < 21){
        int off, hw;
        if (m < 9)       { off = 0;  hw = 9; }
        else if (m < 13) { off = 9;  hw = 4; }
        else if (m < 17) { off = 13; hw = 4; }
        else             { off = 17; hw = 4; }
        const int ml = m - off;
        { // kind 0 (K)
          const int c2 = 2 * ml;
          const int e = c2 >= hw ? 1 : 0, s = c2 - e * hw;
          const uint16_t* src = kvbuf + ((b * 21) + off + s) * 512 + e;
          #pragma unroll
          for (int jj = 0; jj < 8; ++jj) kf[jj] = src[2 * (h * 32 + dch + jj)];
        }
        { // kind 1 (V)
          const int c2 = 2 * ml + 1;
          const int e = c2 >= hw ? 1 : 0, s = c2 - e * hw;
          const uint16_t* src = kvbuf + ((b * 21) + off + s) * 512 + e;
          #pragma unroll
          for (int jj = 0; jj < 8; ++jj) vf[jj] = src[2 * (h * 32 + dch + jj)];
        }
      }
      *reinterpret_cast<u16x8*>(smem + sh4 * 2048 + ((m * 64 + dch * 2) ^ ((m & 7) << 4))) = kf;
      #pragma unroll
      for (int jj = 0; jj < 8; ++jj){
        const int d = dch + jj;
        *reinterpret_cast<uint16_t*>(smem + 8192 + sh4 * 2048 + ((d * 64 + m * 2) ^ ((d & 7) << 4))) = vf[jj];
      }
    }
    __syncthreads();

    const int h4 = w >> 1, wh = w & 1;
    const int hcol = (p * 4 + h4) * 64;   // byte col offset of this head in R1
    const int pabase = 16384 + h4 * 4096;

    // scores: M=32 rows (2 mt), N=32 slots (2 nt), K=32 dims
    bf16x8 bk[2];
    #pragma unroll
    for (int nt = 0; nt < 2; ++nt){
      const int m0 = nt * 16 + (lane & 15);
      bk[nt] = *reinterpret_cast<const bf16x8*>(smem + h4 * 2048 + ((m0 * 64 + (lane >> 4) * 16) ^ ((m0 & 7) << 4)));
    }
    f32x4 sacc[2][2];
    #pragma unroll
    for (int mt = 0; mt < 2; ++mt){
      const int row = wh * 32 + mt * 16 + (lane & 15);
      bf16x8 aq = *reinterpret_cast<const bf16x8*>(smem + OSB + ((row * 512 + hcol + (lane >> 4) * 16) ^ ((row & 7) << 4)));
      #pragma unroll
      for (int nt = 0; nt < 2; ++nt){
        f32x4 z = {};
        sacc[mt][nt] = __builtin_amdgcn_mfma_f32_16x16x32_bf16(aq, bk[nt], z, 0, 0, 0);
      }
    }
    // softmax (21 valid slots) in C-frag layout; P -> PA (pads written 0)
    const bool ok1 = (lane & 15) < 5;
    #pragma unroll
    for (int mt = 0; mt < 2; ++mt)
      #pragma unroll
      for (int i = 0; i < 4; ++i){
        const float s0 = sacc[mt][0][i];
        const float s1 = sacc[mt][1][i];
        float mx = fmaxf(s0, ok1 ? s1 : -3.0e38f);
        #pragma unroll
        for (int dd = 1; dd < 16; dd <<= 1) mx = fmaxf(mx, __shfl_xor(mx, dd));
        const float e0 = __expf(s0 - mx);
        const float e1 = ok1 ? __expf(s1 - mx) : 0.f;
        float sm = e0 + e1;
        #pragma unroll
        for (int dd = 1; dd < 16; dd <<= 1) sm += __shfl_xor(sm, dd);
        const float inv = 1.0f / sm;
        const int pr = wh * 32 + mt * 16 + (lane >> 4) * 4 + i;
        const int c0 = lane & 15;
        *reinterpret_cast<uint16_t*>(smem + pabase + ((pr * 64 + c0 * 2) ^ ((pr & 7) << 4))) = f2bf(e0 * inv);
        *reinterpret_cast<uint16_t*>(smem + pabase + ((pr * 64 + (c0 + 16) * 2) ^ ((pr & 7) << 4))) = f2bf(e1 * inv);
      }
    // PV (produce/consume within wave; no barrier): M=32 rows, N=32 dims, K=32 slots
    f32x4 oacc[2][2];
    #pragma unroll
    for (int mt = 0; mt < 2; ++mt){
      const int pr = wh * 32 + mt * 16 + (lane & 15);
      bf16x8 ap = *reinterpret_cast<const bf16x8*>(smem + pabase + ((pr * 64 + (lane >> 4) * 16) ^ ((pr & 7) << 4)));
      #pragma unroll
      for (int nt = 0; nt < 2; ++nt){
        const int d0 = nt * 16 + (lane & 15);
        bf16x8 bv = *reinterpret_cast<const bf16x8*>(smem + 8192 + h4 * 2048 + ((d0 * 64 + (lane >> 4) * 16) ^ ((d0 & 7) << 4)));
        f32x4 z = {};
        oacc[mt][nt] = __builtin_amdgcn_mfma_f32_16x16x32_bf16(ap, bv, z, 0, 0, 0);
      }
    }
    // O -> R1 (own head cols)
    #pragma unroll
    for (int mt = 0; mt < 2; ++mt)
      #pragma unroll
      for (int nt = 0; nt < 2; ++nt)
        #pragma unroll
        for (int i = 0; i < 4; ++i){
          const int row = wh * 32 + mt * 16 + (lane >> 4) * 4 + i;
          const int colb = hcol + (nt * 16 + (lane & 15)) * 2;
          *reinterpret_cast<uint16_t*>(smem + OSB + ((row * 512 + colb) ^ ((row & 7) << 4))) = f2bf(oacc[mt][nt][i]);
        }
    __syncthreads();
  }

  // ---- out-proj (no barriers; B-frags from global) ----
  f32x4 pacc[4][2] = {};
  #pragma unroll 2
  for (int kt = 0; kt < 8; ++kt){
    bf16x8 a[4];
    #pragma unroll
    for (int mt = 0; mt < 4; ++mt){
      const int row = mt * 16 + (lane & 15);
      a[mt] = *reinterpret_cast<const bf16x8*>(smem + OSB + ((row * 512 + kt * 64 + (lane >> 4) * 16) ^ ((row & 7) << 4)));
    }
    #pragma unroll
    for (int nt = 0; nt < 2; ++nt){
      bf16x8 bfr = *reinterpret_cast<const bf16x8*>(wproj_pk + (size_t)(((w * 2 + nt) * 8 + kt) * 64 + lane) * 8);
      #pragma unroll
      for (int mt = 0; mt < 4; ++mt)
        pacc[mt][nt] = __builtin_amdgcn_mfma_f32_16x16x32_bf16(a[mt], bfr, pacc[mt][nt], 0, 0, 0);
    }
  }
  #pragma unroll
  for (int nt = 0; nt < 2; ++nt){
    const int col = w * 32 + nt * 16 + (lane & 15);
    const float bpv = bproj[col];
    #pragma unroll
    for (int mt = 0; mt < 4; ++mt)
      #pragma unroll
      for (int i = 0; i < 4; ++i){
        const int n = mt * 16 + (lane >> 4) * 4 + i;
        if (n < 49)
          out[(b * 49 + n) * 256 + col] = pacc[mt][nt][i] + bpv;
      }
  }
}

// ---------------------------------------------------------------------------
extern "C" void kernel_launch(void* const* d_in, const int* in_sizes, int n_in,
                              void* d_out, int out_size, void* d_ws, size_t ws_size,
                              hipStream_t stream)
{
  const float* x     = (const float*)d_in[0];
  const float* wq    = (const float*)d_in[1];
  const float* bq    = (const float*)d_in[2];
  const float* wd1   = (const float*)d_in[3];
  const float* bd1   = (const float*)d_in[4];
  const float* wp1   = (const float*)d_in[5];
  const float* bp1   = (const float*)d_in[6];
  const float* wd2   = (const float*)d_in[7];
  const float* bd2   = (const float*)d_in[8];
  const float* wp2   = (const float*)d_in[9];
  const float* bp2   = (const float*)d_in[10];
  const float* wd3   = (const float*)d_in[11];
  const float* bd3   = (const float*)d_in[12];
  const float* wp3   = (const float*)d_in[13];
  const float* bp3   = (const float*)d_in[14];
  const float* wd4   = (const float*)d_in[15];
  const float* bd4   = (const float*)d_in[16];
  const float* wp4   = (const float*)d_in[17];
  const float* bp4   = (const float*)d_in[18];
  const float* wproj = (const float*)d_in[19];
  const float* bproj = (const float*)d_in[20];
  uint16_t* ws = (uint16_t*)d_ws;
  float* out = (float*)d_out;

  k_prepack<<<320, 256, 0, stream>>>(wq, wp1, wp2, wp3, wp4, wproj, ws);
  k_kv<<<512, 512, 86016, stream>>>(x, wd1, bd1, bp1, wd2, bd2, bp2,
                                    wd3, bd3, bp3, wd4, bd4, bp4,
                                    ws, ws + KVBUF);
  k_attn<<<4096, 512, 65536, stream>>>(x, bq, bproj, ws, out);
}

// Round 4
// 277.488 us; speedup vs baseline: 1.4764x; 1.1317x over previous
//
#include <hip/hip_runtime.h>
#include <stdint.h>

typedef __attribute__((ext_vector_type(8))) short bf16x8;
typedef __attribute__((ext_vector_type(8))) unsigned short u16x8;
typedef __attribute__((ext_vector_type(4))) float f32x4;

#define DEV __device__ __forceinline__

// ws layout in ushort elements
constexpr size_t WQ_PK    = 0;         // 65536 elems
constexpr size_t WPROJ_PK = 65536;     // 65536 elems
constexpr size_t WP_PK    = 131072;    // 4 * 131072 elems
constexpr size_t KVBUF    = 655360;    // 4096*21*512 = 44040192 elems
// kvbuf layout: [b][row 0..20 (concat spatial)][o 0..511] bf16 — producer-
// coalesced. Gather permute to (kind,head,slot,dim) happens in k_attn staging
// via stride-2 parity extraction (v_perm) of 32B vector loads.

constexpr float SCALE_Q = 0.17677669529663687f;  // 32^-0.5

DEV uint16_t f2bf(float f){
  uint32_t u = __builtin_bit_cast(uint32_t, f);
  u += 0x7fffu + ((u >> 16) & 1u);
  return (uint16_t)(u >> 16);
}

// extract parity `par` elements of the 16-short window {a,b}:
// out[j] = (j<4 ? a[2j+par] : b[2(j-4)+par])
DEV u16x8 extract_par(u16x8 a, u16x8 b, uint32_t sel){
  union U { u16x8 v; uint32_t d[4]; } A, B, R;
  A.v = a; B.v = b;
  R.d[0] = __builtin_amdgcn_perm(A.d[1], A.d[0], sel);
  R.d[1] = __builtin_amdgcn_perm(A.d[3], A.d[2], sel);
  R.d[2] = __builtin_amdgcn_perm(B.d[1], B.d[0], sel);
  R.d[3] = __builtin_amdgcn_perm(B.d[3], B.d[2], sel);
  return R.v;
}

// ---------------------------------------------------------------------------
// K0: prepack weights into MFMA B-fragment layout, f32 -> bf16.
// ---------------------------------------------------------------------------
__global__ __launch_bounds__(256) void k_prepack(
    const float* __restrict__ wq,  const float* __restrict__ wp1,
    const float* __restrict__ wp2, const float* __restrict__ wp3,
    const float* __restrict__ wp4, const float* __restrict__ wproj,
    uint16_t* __restrict__ ws)
{
  int f = blockIdx.x * 256 + threadIdx.x;   // 0..81919 fragment id
  const float* src; uint16_t* dst; int g;
  if (f < 8192)       { src = wq;    dst = ws + WQ_PK;    g = f; }
  else if (f < 16384) { src = wproj; dst = ws + WPROJ_PK; g = f - 8192; }
  else {
    int j = (f - 16384) >> 14;
    src = j == 0 ? wp1 : j == 1 ? wp2 : j == 2 ? wp3 : wp4;
    dst = ws + WP_PK + (size_t)j * 131072;
    g = (f - 16384) & 16383;
  }
  int l = g & 63, kt = (g >> 6) & 7, nt = g >> 9;
  int n  = nt * 16 + (l & 15);
  int k0 = kt * 32 + (l >> 4) * 8;
  const float* s = src + (size_t)n * 256 + k0;
  u16x8 v;
  #pragma unroll
  for (int j = 0; j < 8; ++j) v[j] = f2bf(s[j]);
  *reinterpret_cast<u16x8*>(dst + (size_t)g * 8) = v;
}

// ---------------------------------------------------------------------------
// K1: depthwise convs + pointwise (MFMA) -> kvbuf2[b][row][o] (bf16).
// 8 batches per block, 512 threads (8 waves). LDS 86016 B.
// dT [168][256] ushort, swizzled: byte = (row*512 + c*2) ^ ((row&7)<<4)
// ---------------------------------------------------------------------------
__global__ __launch_bounds__(512, 2) void k_kv(
    const float* __restrict__ x,
    const float* __restrict__ wd1, const float* __restrict__ bd1, const float* __restrict__ bp1,
    const float* __restrict__ wd2, const float* __restrict__ bd2, const float* __restrict__ bp2,
    const float* __restrict__ wd3, const float* __restrict__ bd3, const float* __restrict__ bp3,
    const float* __restrict__ wd4, const float* __restrict__ bd4, const float* __restrict__ bp4,
    const uint16_t* __restrict__ ws, uint16_t* __restrict__ kvbuf)
{
  extern __shared__ char smem[];  // 86016 B
  const int t = threadIdx.x, lane = t & 63, w = t >> 6;
  const int b0 = blockIdx.x * 8;

  constexpr int DILA[4] = {1,2,3,4}, PADA[4] = {0,0,1,2}, OWA[4] = {3,2,2,2};
  constexpr int HWA[4]  = {9,4,4,4}, OFFA[4] = {0,9,13,17}, MTA[4] = {5,2,2,2};

  // ---- depthwise conv, all branches; write dT (bf16) to LDS ----
  {
    const int c = t & 255, half = t >> 8;
    for (int pass = 0; pass < 4; ++pass){
      const int bh = pass * 2 + half;
      float xr[49];
      #pragma unroll
      for (int p = 0; p < 49; ++p)
        xr[p] = x[((size_t)(b0 + bh) * 49 + p) * 256 + c];
      #pragma unroll
      for (int j = 0; j < 4; ++j){
        const float* wdp = j==0?wd1:j==1?wd2:j==2?wd3:wd4;
        const float* bdp = j==0?bd1:j==1?bd2:j==2?bd3:bd4;
        float wv[9];
        #pragma unroll
        for (int q = 0; q < 9; ++q) wv[q] = wdp[c * 9 + q];
        const float bdv = bdp[c];
        #pragma unroll
        for (int oy = 0; oy < OWA[j]; ++oy)
        #pragma unroll
        for (int ox = 0; ox < OWA[j]; ++ox){
          float acc = bdv;
          #pragma unroll
          for (int ky = 0; ky < 3; ++ky){
            const int yy = oy * 2 - PADA[j] + ky * DILA[j];
            if (yy < 0 || yy > 6) continue;
            #pragma unroll
            for (int kx = 0; kx < 3; ++kx){
              const int xx = ox * 2 - PADA[j] + kx * DILA[j];
              if (xx < 0 || xx > 6) continue;
              acc += xr[yy * 7 + xx] * wv[ky * 3 + kx];
            }
          }
          const int row = bh * 21 + OFFA[j] + oy * OWA[j] + ox;
          *reinterpret_cast<uint16_t*>(smem + ((row * 512 + c * 2) ^ ((row & 7) << 4))) = f2bf(acc);
        }
      }
    }
  }
  __syncthreads();

  // ---- pointwise GEMM per branch; coalesced write to kvbuf2[b][row][o] ----
  // wave w owns output cols [w*64, w*64+64)
  #pragma unroll
  for (int j = 0; j < 4; ++j){
    const uint16_t* pk = ws + WP_PK + (size_t)j * 131072;
    const float* bpp = j==0?bp1:j==1?bp2:j==2?bp3:bp4;
    const int hw = HWA[j], off = OFFA[j], MV = hw * 8;
    float bpv[4];
    #pragma unroll
    for (int nt = 0; nt < 4; ++nt) bpv[nt] = bpp[w * 64 + nt * 16 + (lane & 15)];
    for (int mt = 0; mt < MTA[j]; ++mt){
      f32x4 acc[4] = {};
      const int mrow = mt * 16 + (lane & 15);
      const bool av = mrow < MV;
      const int bh = mrow / hw, s = mrow - bh * hw;
      const int arow = bh * 21 + off + s;
      const int abase = arow * 512 + (lane >> 4) * 16;
      #pragma unroll
      for (int kt = 0; kt < 8; ++kt){
        bf16x8 a = {};
        if (av) a = *reinterpret_cast<const bf16x8*>(smem + ((abase + kt * 64) ^ ((arow & 7) << 4)));
        #pragma unroll
        for (int nt = 0; nt < 4; ++nt){
          const int ntg = w * 4 + nt;
          bf16x8 bfr = *reinterpret_cast<const bf16x8*>(pk + (size_t)((ntg * 8 + kt) * 64 + lane) * 8);
          acc[nt] = __builtin_amdgcn_mfma_f32_16x16x32_bf16(a, bfr, acc[nt], 0, 0, 0);
        }
      }
      const int mr2 = mt * 16 + (lane >> 4) * 4;
      #pragma unroll
      for (int i = 0; i < 4; ++i){
        const int m = mr2 + i;
        if (m >= MV) continue;
        const int bh2 = m / hw, s2 = m - bh2 * hw;
        const size_t grow = ((size_t)(b0 + bh2) * 21 + off + s2) * 512;
        #pragma unroll
        for (int nt = 0; nt < 4; ++nt)
          kvbuf[grow + w * 64 + nt * 16 + (lane & 15)] = f2bf(acc[nt][i] + bpv[nt]);
      }
    }
  }
}

// ---------------------------------------------------------------------------
// K2: fused q-proj + attention + out-proj. 1 batch/block, 512 threads (8
// waves), LDS 64 KB -> 2 blocks/CU. Weights (B-frags) read from global (L2).
// Region R0 [0,32768): x bf16 [64][256] swz; reused per attention pass:
//   KS 4x2KB @0, VT 4x2KB @8192, PA 4x4KB @16384.
// Region R1 [32768,65536): q/O buffer [64][256] us swz.
// kv staging: register-prefetched (T14) + v_perm parity deinterleave.
// ---------------------------------------------------------------------------
__global__ __launch_bounds__(512, 4) void k_attn(
    const float* __restrict__ x, const float* __restrict__ bq,
    const float* __restrict__ bproj, const uint16_t* __restrict__ ws,
    float* __restrict__ out)
{
  extern __shared__ char smem[];   // 65536 B
  constexpr int OSB = 32768;
  const int t = threadIdx.x, lane = t & 63, w = t >> 6;
  const size_t b = blockIdx.x;
  const uint16_t* wq_pk    = ws + WQ_PK;
  const uint16_t* wproj_pk = ws + WPROJ_PK;
  const uint16_t* kvbuf    = ws + KVBUF;

  // ---- stage x -> bf16 [64][256] swz (rows >=49 zeroed) ----
  {
    const int r = t >> 3, c0 = (t & 7) * 32;
    u16x8 vv[4] = {};
    if (r < 49){
      const float* src = x + (b * 49 + r) * 256 + c0;
      #pragma unroll
      for (int jj = 0; jj < 4; ++jj){
        f32x4 f0 = *reinterpret_cast<const f32x4*>(src + jj * 8);
        f32x4 f1 = *reinterpret_cast<const f32x4*>(src + jj * 8 + 4);
        union { u16x8 v; uint32_t d[4]; } R;
        asm("v_cvt_pk_bf16_f32 %0, %1, %2" : "=v"(R.d[0]) : "v"(f0[0]), "v"(f0[1]));
        asm("v_cvt_pk_bf16_f32 %0, %1, %2" : "=v"(R.d[1]) : "v"(f0[2]), "v"(f0[3]));
        asm("v_cvt_pk_bf16_f32 %0, %1, %2" : "=v"(R.d[2]) : "v"(f1[0]), "v"(f1[1]));
        asm("v_cvt_pk_bf16_f32 %0, %1, %2" : "=v"(R.d[3]) : "v"(f1[2]), "v"(f1[3]));
        vv[jj] = R.v;
      }
    }
    #pragma unroll
    for (int jj = 0; jj < 4; ++jj)
      *reinterpret_cast<u16x8*>(smem + ((r * 512 + c0 * 2 + jj * 16) ^ ((r & 7) << 4))) = vv[jj];
  }

  // ---- kv prefetch state (pass 0), issued before q-proj (T14) ----
  const int sh4 = t >> 7, m = (t >> 2) & 31, dch = (t & 3) * 8;
  const bool mv = m < 21;
  uint32_t selK = 0x05040100u, selV = 0x05040100u;
  const uint16_t *rk = kvbuf, *rv = kvbuf;   // safe defaults
  if (mv){
    int off, hw;
    if (m < 9)       { off = 0;  hw = 9; }
    else if (m < 13) { off = 9;  hw = 4; }
    else if (m < 17) { off = 13; hw = 4; }
    else             { off = 17; hw = 4; }
    const int ml = m - off;
    const int c2k = 2 * ml,     ek = c2k >= hw ? 1 : 0, sk = c2k - ek * hw;
    const int c2v = 2 * ml + 1, ev = c2v >= hw ? 1 : 0, sv = c2v - ev * hw;
    selK = ek ? 0x07060302u : 0x05040100u;
    selV = ev ? 0x07060302u : 0x05040100u;
    const int o0 = 2 * (sh4 * 32 + dch);   // pass0 head = sh4
    rk = kvbuf + (b * 21 + off + sk) * 512 + o0;
    rv = kvbuf + (b * 21 + off + sv) * 512 + o0;
  }
  u16x8 L0 = {}, L1 = {}, L2 = {}, L3 = {};
  if (mv){
    L0 = *reinterpret_cast<const u16x8*>(rk);
    L1 = *reinterpret_cast<const u16x8*>(rk + 8);
    L2 = *reinterpret_cast<const u16x8*>(rv);
    L3 = *reinterpret_cast<const u16x8*>(rv + 8);
  }
  __syncthreads();

  // ---- q-proj (no barriers; B-frags from global) ----
  f32x4 qacc[4][2] = {};
  #pragma unroll 2
  for (int kt = 0; kt < 8; ++kt){
    bf16x8 a[4];
    #pragma unroll
    for (int mt = 0; mt < 4; ++mt){
      const int row = mt * 16 + (lane & 15);
      a[mt] = *reinterpret_cast<const bf16x8*>(smem + ((row * 512 + kt * 64 + (lane >> 4) * 16) ^ ((row & 7) << 4)));
    }
    #pragma unroll
    for (int nt = 0; nt < 2; ++nt){
      bf16x8 bfr = *reinterpret_cast<const bf16x8*>(wq_pk + (size_t)(((w * 2 + nt) * 8 + kt) * 64 + lane) * 8);
      #pragma unroll
      for (int mt = 0; mt < 4; ++mt)
        qacc[mt][nt] = __builtin_amdgcn_mfma_f32_16x16x32_bf16(a[mt], bfr, qacc[mt][nt], 0, 0, 0);
    }
  }
  // q (bias+scale, bf16) -> R1
  #pragma unroll
  for (int nt = 0; nt < 2; ++nt){
    const int col = w * 32 + nt * 16 + (lane & 15);
    const float bqv = bq[col];
    #pragma unroll
    for (int mt = 0; mt < 4; ++mt)
      #pragma unroll
      for (int i = 0; i < 4; ++i){
        const int row = mt * 16 + (lane >> 4) * 4 + i;
        *reinterpret_cast<uint16_t*>(smem + OSB + ((row * 512 + col * 2) ^ ((row & 7) << 4)))
          = f2bf((qacc[mt][nt][i] + bqv) * SCALE_Q);
      }
  }
  __syncthreads();   // x consumed; R0 free for KS/VT/PA

  // ---- attention: 2 passes x 4 heads, 2 waves/head ----
  for (int p = 0; p < 2; ++p){
    { // extract prefetched kv -> KS (vector) / VT (transposed scatter)
      u16x8 kf = extract_par(L0, L1, selK);
      u16x8 vf = extract_par(L2, L3, selV);
      *reinterpret_cast<u16x8*>(smem + sh4 * 2048 + ((m * 64 + dch * 2) ^ ((m & 7) << 4))) = kf;
      #pragma unroll
      for (int jj = 0; jj < 8; ++jj){
        const int d = dch + jj;
        *reinterpret_cast<uint16_t*>(smem + 8192 + sh4 * 2048 + ((d * 64 + m * 2) ^ ((d & 7) << 4))) = vf[jj];
      }
      if (p == 0 && mv){  // prefetch pass-1 (head = 4+sh4 -> +256 elems)
        L0 = *reinterpret_cast<const u16x8*>(rk + 256);
        L1 = *reinterpret_cast<const u16x8*>(rk + 264);
        L2 = *reinterpret_cast<const u16x8*>(rv + 256);
        L3 = *reinterpret_cast<const u16x8*>(rv + 264);
      }
    }
    __syncthreads();

    const int h4 = w >> 1, wh = w & 1;
    const int hcol = (p * 4 + h4) * 64;   // byte col offset of this head in R1
    const int pabase = 16384 + h4 * 4096;

    // scores: M=32 rows (2 mt), N=32 slots (2 nt), K=32 dims
    bf16x8 bk[2];
    #pragma unroll
    for (int nt = 0; nt < 2; ++nt){
      const int m0 = nt * 16 + (lane & 15);
      bk[nt] = *reinterpret_cast<const bf16x8*>(smem + h4 * 2048 + ((m0 * 64 + (lane >> 4) * 16) ^ ((m0 & 7) << 4)));
    }
    f32x4 sacc[2][2];
    #pragma unroll
    for (int mt = 0; mt < 2; ++mt){
      const int row = wh * 32 + mt * 16 + (lane & 15);
      bf16x8 aq = *reinterpret_cast<const bf16x8*>(smem + OSB + ((row * 512 + hcol + (lane >> 4) * 16) ^ ((row & 7) << 4)));
      #pragma unroll
      for (int nt = 0; nt < 2; ++nt){
        f32x4 z = {};
        sacc[mt][nt] = __builtin_amdgcn_mfma_f32_16x16x32_bf16(aq, bk[nt], z, 0, 0, 0);
      }
    }
    // softmax (21 valid slots) in C-frag layout; P -> PA (pads written 0)
    const bool ok1 = (lane & 15) < 5;
    #pragma unroll
    for (int mt = 0; mt < 2; ++mt)
      #pragma unroll
      for (int i = 0; i < 4; ++i){
        const float s0 = sacc[mt][0][i];
        const float s1 = sacc[mt][1][i];
        float mx = fmaxf(s0, ok1 ? s1 : -3.0e38f);
        #pragma unroll
        for (int dd = 1; dd < 16; dd <<= 1) mx = fmaxf(mx, __shfl_xor(mx, dd));
        const float e0 = __expf(s0 - mx);
        const float e1 = ok1 ? __expf(s1 - mx) : 0.f;
        float sm = e0 + e1;
        #pragma unroll
        for (int dd = 1; dd < 16; dd <<= 1) sm += __shfl_xor(sm, dd);
        const float inv = 1.0f / sm;
        const int pr = wh * 32 + mt * 16 + (lane >> 4) * 4 + i;
        const int c0 = lane & 15;
        *reinterpret_cast<uint16_t*>(smem + pabase + ((pr * 64 + c0 * 2) ^ ((pr & 7) << 4))) = f2bf(e0 * inv);
        *reinterpret_cast<uint16_t*>(smem + pabase + ((pr * 64 + (c0 + 16) * 2) ^ ((pr & 7) << 4))) = f2bf(e1 * inv);
      }
    // PV (produce/consume within wave; no barrier): M=32 rows, N=32 dims, K=32 slots
    f32x4 oacc[2][2];
    #pragma unroll
    for (int mt = 0; mt < 2; ++mt){
      const int pr = wh * 32 + mt * 16 + (lane & 15);
      bf16x8 ap = *reinterpret_cast<const bf16x8*>(smem + pabase + ((pr * 64 + (lane >> 4) * 16) ^ ((pr & 7) << 4)));
      #pragma unroll
      for (int nt = 0; nt < 2; ++nt){
        const int d0 = nt * 16 + (lane & 15);
        bf16x8 bv = *reinterpret_cast<const bf16x8*>(smem + 8192 + h4 * 2048 + ((d0 * 64 + (lane >> 4) * 16) ^ ((d0 & 7) << 4)));
        f32x4 z = {};
        oacc[mt][nt] = __builtin_amdgcn_mfma_f32_16x16x32_bf16(ap, bv, z, 0, 0, 0);
      }
    }
    // O -> R1 (own head cols)
    #pragma unroll
    for (int mt = 0; mt < 2; ++mt)
      #pragma unroll
      for (int nt = 0; nt < 2; ++nt)
        #pragma unroll
        for (int i = 0; i < 4; ++i){
          const int row = wh * 32 + mt * 16 + (lane >> 4) * 4 + i;
          const int colb = hcol + (nt * 16 + (lane & 15)) * 2;
          *reinterpret_cast<uint16_t*>(smem + OSB + ((row * 512 + colb) ^ ((row & 7) << 4))) = f2bf(oacc[mt][nt][i]);
        }
    __syncthreads();
  }

  // ---- out-proj (no barriers; B-frags from global) ----
  f32x4 pacc[4][2] = {};
  #pragma unroll 2
  for (int kt = 0; kt < 8; ++kt){
    bf16x8 a[4];
    #pragma unroll
    for (int mt = 0; mt < 4; ++mt){
      const int row = mt * 16 + (lane & 15);
      a[mt] = *reinterpret_cast<const bf16x8*>(smem + OSB + ((row * 512 + kt * 64 + (lane >> 4) * 16) ^ ((row & 7) << 4)));
    }
    #pragma unroll
    for (int nt = 0; nt < 2; ++nt){
      bf16x8 bfr = *reinterpret_cast<const bf16x8*>(wproj_pk + (size_t)(((w * 2 + nt) * 8 + kt) * 64 + lane) * 8);
      #pragma unroll
      for (int mt = 0; mt < 4; ++mt)
        pacc[mt][nt] = __builtin_amdgcn_mfma_f32_16x16x32_bf16(a[mt], bfr, pacc[mt][nt], 0, 0, 0);
    }
  }
  #pragma unroll
  for (int nt = 0; nt < 2; ++nt){
    const int col = w * 32 + nt * 16 + (lane & 15);
    const float bpv = bproj[col];
    #pragma unroll
    for (int mt = 0; mt < 4; ++mt)
      #pragma unroll
      for (int i = 0; i < 4; ++i){
        const int n = mt * 16 + (lane >> 4) * 4 + i;
        if (n < 49)
          out[(b * 49 + n) * 256 + col] = pacc[mt][nt][i] + bpv;
      }
  }
}

// ---------------------------------------------------------------------------
extern "C" void kernel_launch(void* const* d_in, const int* in_sizes, int n_in,
                              void* d_out, int out_size, void* d_ws, size_t ws_size,
                              hipStream_t stream)
{
  const float* x     = (const float*)d_in[0];
  const float* wq    = (const float*)d_in[1];
  const float* bq    = (const float*)d_in[2];
  const float* wd1   = (const float*)d_in[3];
  const float* bd1   = (const float*)d_in[4];
  const float* wp1   = (const float*)d_in[5];
  const float* bp1   = (const float*)d_in[6];
  const float* wd2   = (const float*)d_in[7];
  const float* bd2   = (const float*)d_in[8];
  const float* wp2   = (const float*)d_in[9];
  const float* bp2   = (const float*)d_in[10];
  const float* wd3   = (const float*)d_in[11];
  const float* bd3   = (const float*)d_in[12];
  const float* wp3   = (const float*)d_in[13];
  const float* bp3   = (const float*)d_in[14];
  const float* wd4   = (const float*)d_in[15];
  const float* bd4   = (const float*)d_in[16];
  const float* wp4   = (const float*)d_in[17];
  const float* bp4   = (const float*)d_in[18];
  const float* wproj = (const float*)d_in[19];
  const float* bproj = (const float*)d_in[20];
  uint16_t* ws = (uint16_t*)d_ws;
  float* out = (float*)d_out;

  k_prepack<<<320, 256, 0, stream>>>(wq, wp1, wp2, wp3, wp4, wproj, ws);
  k_kv<<<512, 512, 86016, stream>>>(x, wd1, bd1, bp1, wd2, bd2, bp2,
                                    wd3, bd3, bp3, wd4, bd4, bp4,
                                    ws, ws + KVBUF);
  k_attn<<<4096, 512, 65536, stream>>>(x, bq, bproj, ws, out);
}